// Round 1
// baseline (109.209 us; speedup 1.0000x reference)
//
#include <hip/hip_runtime.h>
#include <hip/hip_bf16.h>
#include <stdint.h>

// Shapes (fixed by the problem)
constexpr int Bsz = 4;
constexpr int Nseq = 1024;
constexpr int Cdim = 1024;
constexpr int Mrows = Bsz * Nseq;   // 4096

typedef __attribute__((ext_vector_type(4))) short s16x4;
typedef __attribute__((ext_vector_type(8))) short s16x8;
typedef __attribute__((ext_vector_type(4))) float f32x4;

__device__ inline short bf16_rne(float f) {
    union { float f; unsigned u; } c; c.f = f;
    unsigned u = c.u;
    u = u + 0x7FFFu + ((u >> 16) & 1u);
    return (short)(u >> 16);
}

__device__ inline s16x4 cvt4(float4 v) {
    s16x4 r;
    r[0] = bf16_rne(v.x); r[1] = bf16_rne(v.y);
    r[2] = bf16_rne(v.z); r[3] = bf16_rne(v.w);
    return r;
}

// C[M][N] = A[M][K] @ W[N][K]^T + bias[N]
// 128x128 block tile, 4 waves (2x2), each wave 64x64 = 4x4 MFMA frags, BK=32.
constexpr int LDT = 72;  // LDS row stride in bf16 elems: 144B = 9*16B (aligned), 36 banks -> 2-way (free)

__global__ __launch_bounds__(256) void gemm_bt_bias(const float* __restrict__ A,
                                                    const float* __restrict__ W,
                                                    const float* __restrict__ bias,
                                                    float* __restrict__ Cmat,
                                                    int K, int Ncols) {
    __shared__ short As[128 * LDT];
    __shared__ short Bs[128 * LDT];
    const int tid  = threadIdx.x;
    const int lane = tid & 63;
    const int wave = tid >> 6;
    const int wr = wave >> 1;
    const int wc = wave & 1;
    const int fr = lane & 15;
    const int kq = (lane >> 4) * 8;

    const int arow0 = blockIdx.y * 128;
    const int ncol0 = blockIdx.x * 128;

    f32x4 acc[4][4] = {};

    const int sr = tid >> 3;        // 0..31 (row within a 32-row pass)
    const int sc = (tid & 7) * 4;   // 0..28 (k-col, float4 granularity)

    for (int k0 = 0; k0 < K; k0 += 32) {
        __syncthreads();   // protect LDS from previous iteration's readers
        #pragma unroll
        for (int p = 0; p < 4; ++p) {
            const int r = sr + p * 32;
            const float4 av = *(const float4*)(A + (size_t)(arow0 + r) * K + k0 + sc);
            const float4 wv = *(const float4*)(W + (size_t)(ncol0 + r) * K + k0 + sc);
            *(s16x4*)&As[r * LDT + sc] = cvt4(av);
            *(s16x4*)&Bs[r * LDT + sc] = cvt4(wv);
        }
        __syncthreads();

        s16x8 af[4], bfr[4];
        #pragma unroll
        for (int mi = 0; mi < 4; ++mi)
            af[mi] = *(const s16x8*)&As[(wr * 64 + mi * 16 + fr) * LDT + kq];
        #pragma unroll
        for (int ni = 0; ni < 4; ++ni)
            bfr[ni] = *(const s16x8*)&Bs[(wc * 64 + ni * 16 + fr) * LDT + kq];

        #pragma unroll
        for (int mi = 0; mi < 4; ++mi)
            #pragma unroll
            for (int ni = 0; ni < 4; ++ni)
                acc[mi][ni] = __builtin_amdgcn_mfma_f32_16x16x32_bf16(
                    af[mi], bfr[ni], acc[mi][ni], 0, 0, 0);
    }

    // Epilogue: C/D layout (m89-verified): col = lane&15, row = (lane>>4)*4 + reg
    #pragma unroll
    for (int mi = 0; mi < 4; ++mi) {
        const int row0 = arow0 + wr * 64 + mi * 16 + (lane >> 4) * 4;
        #pragma unroll
        for (int ni = 0; ni < 4; ++ni) {
            const int col = ncol0 + wc * 64 + ni * 16 + fr;
            const float bs = bias[col];
            f32x4 r = acc[mi][ni];
            #pragma unroll
            for (int j = 0; j < 4; ++j)
                Cmat[(size_t)(row0 + j) * Ncols + col] = r[j] + bs;
        }
    }
}

// Per output row (b,i): find max relation id over j, average V rows of the argmax set.
// Deterministic (prefix-scan compaction, ascending j order).
__global__ __launch_bounds__(256) void mask_avg_kernel(const int* __restrict__ mask,
                                                       const float* __restrict__ V,
                                                       float* __restrict__ Y) {
    const int row = blockIdx.x;          // b*N + i
    const int tid = threadIdx.x;
    const int b = row >> 10;
    const int* mrow = mask + (size_t)row * Nseq;

    __shared__ int wmax[4];
    __shared__ int pre[256];
    __shared__ int idx[1024];

    const int4 mv = ((const int4*)mrow)[tid];
    int lm = max(max(mv.x, mv.y), max(mv.z, mv.w));
    #pragma unroll
    for (int off = 32; off > 0; off >>= 1) lm = max(lm, __shfl_xor(lm, off));
    if ((tid & 63) == 0) wmax[tid >> 6] = lm;
    __syncthreads();
    const int gmax = max(max(wmax[0], wmax[1]), max(wmax[2], wmax[3]));

    const int loc = (mv.x == gmax) + (mv.y == gmax) + (mv.z == gmax) + (mv.w == gmax);
    pre[tid] = loc;
    __syncthreads();
    // Hillis-Steele inclusive scan over 256 threads
    for (int off = 1; off < 256; off <<= 1) {
        const int v   = pre[tid];
        const int add = (tid >= off) ? pre[tid - off] : 0;
        __syncthreads();
        pre[tid] = v + add;
        __syncthreads();
    }
    int pos = pre[tid] - loc;   // exclusive prefix
    if (mv.x == gmax) idx[pos++] = tid * 4 + 0;
    if (mv.y == gmax) idx[pos++] = tid * 4 + 1;
    if (mv.z == gmax) idx[pos++] = tid * 4 + 2;
    if (mv.w == gmax) idx[pos++] = tid * 4 + 3;
    __syncthreads();
    const int n = pre[255];

    const float* Vb = V + (size_t)(b << 10) * Cdim;
    float4 acc = make_float4(0.f, 0.f, 0.f, 0.f);
    for (int t = 0; t < n; ++t) {
        const float4 v = *(const float4*)(Vb + (size_t)idx[t] * Cdim + tid * 4);
        acc.x += v.x; acc.y += v.y; acc.z += v.z; acc.w += v.w;
    }
    const float inv = 1.0f / (float)n;
    float4 o; o.x = acc.x * inv; o.y = acc.y * inv; o.z = acc.z * inv; o.w = acc.w * inv;
    *(float4*)(Y + (size_t)row * Cdim + tid * 4) = o;
}

extern "C" void kernel_launch(void* const* d_in, const int* in_sizes, int n_in,
                              void* d_out, int out_size, void* d_ws, size_t ws_size,
                              hipStream_t stream) {
    const float* x      = (const float*)d_in[0];
    const int*   mask   = (const int*)d_in[1];
    const float* qkv_w  = (const float*)d_in[2];
    const float* qkv_b  = (const float*)d_in[3];
    const float* proj_w = (const float*)d_in[4];
    const float* proj_b = (const float*)d_in[5];
    // d_in[6] (rel_emb) is numerically dead in the f32 reference (see analysis).
    float* out = (float*)d_out;

    float* V = (float*)d_ws;                      // [4096][1024] f32, 16 MiB
    float* Y = V + (size_t)Mrows * Cdim;          // [4096][1024] f32, 16 MiB

    const float* Wv = qkv_w + (size_t)2 * Cdim * Cdim;  // V-projection rows of qkv_w
    const float* bv = qkv_b + 2 * Cdim;

    dim3 gg(Cdim / 128, Mrows / 128);   // 8 x 32 = 256 blocks

    // 1) V = x @ Wv^T + bv
    gemm_bt_bias<<<gg, 256, 0, stream>>>(x, Wv, bv, V, Cdim, Cdim);
    // 2) Y[b,i,:] = mean over argmax-mask columns of V[b,:,:]
    mask_avg_kernel<<<dim3(Mrows), 256, 0, stream>>>(mask, V, Y);
    // 3) out = Y @ proj_w^T + proj_b
    gemm_bt_bias<<<gg, 256, 0, stream>>>(Y, proj_w, proj_b, out, Cdim, Cdim);
}

// Round 2
// 66.198 us; speedup vs baseline: 1.6497x; 1.6497x over previous
//
#include <hip/hip_runtime.h>
#include <hip/hip_bf16.h>
#include <stdint.h>

// Shapes (fixed by the problem)
constexpr int Bsz  = 4;
constexpr int Nseq = 1024;
constexpr int Cdim = 1024;
constexpr int Mrows = Bsz * Nseq;   // 4096
constexpr int KD = Cdim;            // GEMM K
constexpr int BM = 64, BN = 128, BK = 64;
constexpr int NT = KD / BK;         // 16 K-steps

typedef __attribute__((ext_vector_type(8))) short s16x8;
typedef __attribute__((ext_vector_type(4))) float f32x4;
typedef __attribute__((address_space(3))) unsigned char lds_b;
typedef __attribute__((address_space(1))) const unsigned char gbl_b;

__device__ inline short bf16_rne(float f) {
    union { float f; unsigned u; } c; c.f = f;
    unsigned u = c.u;
    u = u + 0x7FFFu + ((u >> 16) & 1u);
    return (short)(u >> 16);
}
__device__ inline float bf2f(unsigned short u) {
    union { unsigned u; float f; } c; c.u = ((unsigned)u) << 16;
    return c.f;
}

// f32 -> bf16 convert: x (4096x1024), Wv (1024x1024), proj_w (1024x1024)
__global__ __launch_bounds__(256) void cvt_bf16_3(const float* __restrict__ x,
                                                  const float* __restrict__ wv,
                                                  const float* __restrict__ pw,
                                                  ushort* __restrict__ xb,
                                                  ushort* __restrict__ wvb,
                                                  ushort* __restrict__ pwb) {
    constexpr int NX = Mrows * Cdim / 4;   // 1048576 float4s
    constexpr int NW = Cdim * Cdim / 4;    // 262144
    constexpr int total = NX + 2 * NW;
    for (int i = blockIdx.x * 256 + threadIdx.x; i < total; i += gridDim.x * 256) {
        const float* s; ushort* d; int j;
        if (i < NX)           { s = x;  d = xb;  j = i; }
        else if (i < NX + NW) { s = wv; d = wvb; j = i - NX; }
        else                  { s = pw; d = pwb; j = i - NX - NW; }
        const float4 v = ((const float4*)s)[j];
        ushort4 o;
        o.x = (ushort)bf16_rne(v.x); o.y = (ushort)bf16_rne(v.y);
        o.z = (ushort)bf16_rne(v.z); o.w = (ushort)bf16_rne(v.w);
        ((ushort4*)d)[j] = o;
    }
}

// C[M][N] = A[M][K] @ W[N][K]^T + bias[N], bf16 operands, f32 accum.
// 64x128 tile, 4 waves (2x2, each 32x64 = 2x4 frags of 16x16x32), BK=64,
// double-buffered global_load_lds staging with XOR slot-swizzle (slot ^= row&7).
template <bool OUT_BF16>
__global__ __launch_bounds__(256) void gemm_bt(const ushort* __restrict__ A,
                                               const ushort* __restrict__ W,
                                               const float* __restrict__ bias,
                                               void* __restrict__ Cout,
                                               int Ncols) {
    __shared__ short As[2][BM * BK];
    __shared__ short Bs[2][BN * BK];
    const int tid  = threadIdx.x;
    const int lane = tid & 63;
    const int w    = tid >> 6;
    const int wr = w >> 1;          // row half (32 rows)
    const int wc = w & 1;           // col half (64 cols)
    const int fr = lane & 15;
    const int kg = lane >> 4;       // 0..3
    const int lr = lane >> 3;       // staging: row within 8-row group
    const int cs = lane & 7;        // staging: 16B slot within row

    const int arow0 = blockIdx.y * BM;
    const int ncol0 = blockIdx.x * BN;

    auto stage = [&](int b, int k0) {
        #pragma unroll
        for (int c = 0; c < 2; ++c) {           // A: 16 rows per wave
            const int r  = w * 16 + c * 8 + lr;
            const int gs = cs ^ (r & 7);        // pre-swizzled global source slot
            __builtin_amdgcn_global_load_lds(
                (gbl_b*)(A + (size_t)(arow0 + r) * KD + k0 + gs * 8),
                (lds_b*)&As[b][(w * 16 + c * 8) * BK], 16, 0, 0);
        }
        #pragma unroll
        for (int c = 0; c < 4; ++c) {           // B: 32 rows per wave
            const int r  = w * 32 + c * 8 + lr;
            const int gs = cs ^ (r & 7);
            __builtin_amdgcn_global_load_lds(
                (gbl_b*)(W + (size_t)(ncol0 + r) * KD + k0 + gs * 8),
                (lds_b*)&Bs[b][(w * 32 + c * 8) * BK], 16, 0, 0);
        }
    };

    f32x4 acc[2][4] = {};

    stage(0, 0);
    __syncthreads();   // vmcnt(0) drain + barrier: buf0 ready

    for (int t = 0; t < NT; ++t) {
        const int cur = t & 1;
        if (t + 1 < NT) stage(cur ^ 1, (t + 1) * BK);   // prefetch overlaps MFMA

        s16x8 af[2][2], bv[4][2];
        #pragma unroll
        for (int mi = 0; mi < 2; ++mi)
            #pragma unroll
            for (int ks = 0; ks < 2; ++ks) {
                const int row = wr * 32 + mi * 16 + fr;
                const int sl  = (ks * 4 + kg) ^ (row & 7);   // swizzled read
                af[mi][ks] = *(const s16x8*)&As[cur][row * BK + sl * 8];
            }
        #pragma unroll
        for (int ni = 0; ni < 4; ++ni)
            #pragma unroll
            for (int ks = 0; ks < 2; ++ks) {
                const int row = wc * 64 + ni * 16 + fr;
                const int sl  = (ks * 4 + kg) ^ (row & 7);
                bv[ni][ks] = *(const s16x8*)&Bs[cur][row * BK + sl * 8];
            }

        #pragma unroll
        for (int ks = 0; ks < 2; ++ks)
            #pragma unroll
            for (int mi = 0; mi < 2; ++mi)
                #pragma unroll
                for (int ni = 0; ni < 4; ++ni)
                    acc[mi][ni] = __builtin_amdgcn_mfma_f32_16x16x32_bf16(
                        af[mi][ks], bv[ni][ks], acc[mi][ni], 0, 0, 0);

        __syncthreads();   // drains vmcnt (next-tile loads) + lgkm, barrier
    }

    // Epilogue. C/D layout (m89-verified): col = lane&15, row = (lane>>4)*4 + j
    #pragma unroll
    for (int mi = 0; mi < 2; ++mi) {
        const int row0 = arow0 + wr * 32 + mi * 16 + kg * 4;
        #pragma unroll
        for (int ni = 0; ni < 4; ++ni) {
            const int col = ncol0 + wc * 64 + ni * 16 + fr;
            const float bs = bias[col];
            f32x4 r = acc[mi][ni];
            if (OUT_BF16) {
                ushort* o = (ushort*)Cout;
                #pragma unroll
                for (int j = 0; j < 4; ++j)
                    o[(size_t)(row0 + j) * Ncols + col] = (ushort)bf16_rne(r[j] + bs);
            } else {
                float* o = (float*)Cout;
                #pragma unroll
                for (int j = 0; j < 4; ++j)
                    o[(size_t)(row0 + j) * Ncols + col] = r[j] + bs;
            }
        }
    }
}

// Per output row (b,i): find max relation id over j, average bf16-V rows of the
// argmax set (deterministic prefix-scan compaction), write bf16 Y.
__global__ __launch_bounds__(256) void mask_avg_kernel(const int* __restrict__ mask,
                                                       const ushort* __restrict__ V,
                                                       ushort* __restrict__ Y) {
    const int row = blockIdx.x;          // b*N + i
    const int tid = threadIdx.x;
    const int b = row >> 10;
    const int* mrow = mask + (size_t)row * Nseq;

    __shared__ int wmax[4];
    __shared__ int pre[256];
    __shared__ int idx[1024];

    const int4 mv = ((const int4*)mrow)[tid];
    int lm = max(max(mv.x, mv.y), max(mv.z, mv.w));
    #pragma unroll
    for (int off = 32; off > 0; off >>= 1) lm = max(lm, __shfl_xor(lm, off));
    if ((tid & 63) == 0) wmax[tid >> 6] = lm;
    __syncthreads();
    const int gmax = max(max(wmax[0], wmax[1]), max(wmax[2], wmax[3]));

    const int loc = (mv.x == gmax) + (mv.y == gmax) + (mv.z == gmax) + (mv.w == gmax);
    pre[tid] = loc;
    __syncthreads();
    for (int off = 1; off < 256; off <<= 1) {   // Hillis-Steele inclusive scan
        const int v   = pre[tid];
        const int add = (tid >= off) ? pre[tid - off] : 0;
        __syncthreads();
        pre[tid] = v + add;
        __syncthreads();
    }
    int pos = pre[tid] - loc;
    if (mv.x == gmax) idx[pos++] = tid * 4 + 0;
    if (mv.y == gmax) idx[pos++] = tid * 4 + 1;
    if (mv.z == gmax) idx[pos++] = tid * 4 + 2;
    if (mv.w == gmax) idx[pos++] = tid * 4 + 3;
    __syncthreads();
    const int n = pre[255];

    const ushort* Vb = V + (size_t)(b << 10) * Cdim;
    float4 acc = make_float4(0.f, 0.f, 0.f, 0.f);
    for (int t = 0; t < n; ++t) {
        const ushort4 v = *(const ushort4*)(Vb + (size_t)idx[t] * Cdim + tid * 4);
        acc.x += bf2f(v.x); acc.y += bf2f(v.y);
        acc.z += bf2f(v.z); acc.w += bf2f(v.w);
    }
    const float inv = 1.0f / (float)n;
    ushort4 o;
    o.x = (ushort)bf16_rne(acc.x * inv); o.y = (ushort)bf16_rne(acc.y * inv);
    o.z = (ushort)bf16_rne(acc.z * inv); o.w = (ushort)bf16_rne(acc.w * inv);
    *(ushort4*)(Y + (size_t)row * Cdim + tid * 4) = o;
}

extern "C" void kernel_launch(void* const* d_in, const int* in_sizes, int n_in,
                              void* d_out, int out_size, void* d_ws, size_t ws_size,
                              hipStream_t stream) {
    const float* x      = (const float*)d_in[0];
    const int*   mask   = (const int*)d_in[1];
    const float* qkv_w  = (const float*)d_in[2];
    const float* qkv_b  = (const float*)d_in[3];
    const float* proj_w = (const float*)d_in[4];
    const float* proj_b = (const float*)d_in[5];
    // d_in[6] (rel_emb) is numerically dead in the f32 reference (annihilated by
    // the (m-1)*1e9 offsets; softmax reduces to uniform avg over argmax-m set).
    float* out = (float*)d_out;

    // Workspace layout (bf16 elements): 28 MB total
    ushort* xb  = (ushort*)d_ws;                     // [4096][1024]
    ushort* wvb = xb  + (size_t)Mrows * Cdim;        // [1024][1024]
    ushort* pwb = wvb + (size_t)Cdim * Cdim;         // [1024][1024]
    ushort* V   = pwb + (size_t)Cdim * Cdim;         // [4096][1024]
    ushort* Y   = V   + (size_t)Mrows * Cdim;        // [4096][1024]

    const float* Wv = qkv_w + (size_t)2 * Cdim * Cdim;
    const float* bv = qkv_b + 2 * Cdim;

    cvt_bf16_3<<<2048, 256, 0, stream>>>(x, Wv, proj_w, xb, wvb, pwb);

    dim3 gg(Cdim / BN, Mrows / BM);   // 8 x 64 = 512 blocks (2 per CU)

    // 1) V = bf16(x @ Wv^T + bv)
    gemm_bt<true><<<gg, 256, 0, stream>>>(xb, wvb, bv, V, Cdim);
    // 2) Y[b,i,:] = mean over argmax-mask rows of V[b,:,:]
    mask_avg_kernel<<<dim3(Mrows), 256, 0, stream>>>(mask, V, Y);
    // 3) out = Y @ proj_w^T + proj_b
    gemm_bt<false><<<gg, 256, 0, stream>>>(Y, pwb, proj_b, out, Cdim);
}